// Round 19
// baseline (576.721 us; speedup 1.0000x reference)
//
#include <hip/hip_runtime.h>
#include <hip/hip_fp16.h>

// ---------------------------------------------------------------------------
// GraphAttention on MI355X (gfx950). f16 MFMA, fp32 accum.
// R19 = R18 (best: 474.6 us) + two launch-count reductions:
//  - detect_fmt folded into prep_main's adj branch (each adj block re-derives
//    the format flag from adj[0:4096] locally; removes the 1-block dispatch)
//  - independent tail GEMMs hf+ha merged into one gemm_hfha dispatch
//    (bid-range decode; gemm_core takes explicit bid)
// 13 -> 11 dispatches. GEMM core byte-identical to R18 (64x256 tile, 4 waves,
// single-buffer 2-barrier loop, z->XCD pinning, fused epilogues).
// ---------------------------------------------------------------------------

typedef _Float16 h8 __attribute__((ext_vector_type(8)));
typedef _Float16 h4 __attribute__((ext_vector_type(4)));
typedef float f4 __attribute__((ext_vector_type(4)));

__device__ __forceinline__ void load_lds16(const void* g, void* l) {
  __builtin_amdgcn_global_load_lds(
      (const __attribute__((address_space(1))) unsigned int*)g,
      (__attribute__((address_space(3))) unsigned int*)l, 16, 0, 0);
}

struct GP {
  const _Float16* A; const _Float16* B; void* C; const float* bias;
  const unsigned long long* adjb; _Float16* aux;
  int K, ldA, ldB, ldC, z0, ntx, nty, nz;
  long sAz, sAb, sBz, sBh, sCz, sCb, sCh, sBiasH, sAuxZ;
};

// Stage A (64x64, chunks 0..7) and B (256x64, chunks 8..39) into LDS.
// Element (row,k) lives at byte row*128 + ((2k) ^ ((row&7)<<4)).
__device__ __forceinline__ void stage_tiles5(const _Float16* Ag, const _Float16* Bg,
                                             _Float16* As, _Float16* Bs,
                                             int ldA, int ldB, int wv, int rs, int cs) {
#pragma unroll
  for (int ps = 0; ps < 10; ++ps) {
    int c = ps * 4 + wv;            // 0..39, wave-uniform
    if (c < 8) {
      int r = c * 8 + rs;           // A row 0..63
      int kb = (cs ^ (r & 7)) * 8;
      load_lds16(Ag + (long)r * ldA + kb, As + c * 512);
    } else {
      int cb = c - 8;
      int r = cb * 8 + rs;          // B row 0..255
      int kb = (cs ^ (r & 7)) * 8;
      load_lds16(Bg + (long)r * ldB + kb, Bs + cb * 512);
    }
  }
}

__device__ __forceinline__ void compute_tile5(const _Float16* As, const _Float16* Bs,
                                              f4 acc[4][4], int wv, int l15, int lg) {
#pragma unroll
  for (int ks = 0; ks < 2; ++ks) {
    const int kby = ks * 64 + lg * 16;
    h8 av[4], bv[4];
#pragma unroll
    for (int m = 0; m < 4; ++m) {
      int row = m * 16 + l15;                       // 0..63
      av[m] = *(const h8*)((const char*)As + row * 128 + (kby ^ ((row & 7) << 4)));
    }
#pragma unroll
    for (int n = 0; n < 4; ++n) {
      int col = wv * 64 + n * 16 + l15;             // 0..255
      bv[n] = *(const h8*)((const char*)Bs + col * 128 + (kby ^ ((col & 7) << 4)));
    }
#pragma unroll
    for (int m = 0; m < 4; ++m)
#pragma unroll
      for (int n = 0; n < 4; ++n)
        acc[m][n] = __builtin_amdgcn_mfma_f32_16x16x32_f16(av[m], bv[n], acc[m][n], 0, 0, 0);
  }
}

// BT-GEMM body: C[M,N] = A[M,K]*B[N,K]^T, 64x256 tile, BK=64, 4 waves
// (1M x 4N, per-wave 64x64), single-buffered 40KB LDS, 2 barriers/K-step,
// 1D XCD-aware decode on explicit bid, single-pass f16-LDS epilogue.
// EPI: 0 f16 | 2 mask+tanh f16 | 3 relu f16
//      | 5 bias+sigmoid, fused mix (reads aux=gcat, writes fp32 out)
//      | 6 bias f16 + dual store (C and aux=C^T)
template<int EPI>
__device__ __forceinline__ void gemm_core(GP p, int bid) {
  __shared__ __align__(16) char smem[40960];
  _Float16* Ash = (_Float16*)smem;                    // [64*64] f16, 8KB
  _Float16* Bsh = (_Float16*)(smem + 8192);           // [256*64] f16, 32KB
  _Float16* Cld = (_Float16*)smem;                    // epilogue alias, 32KB

  const int tid = threadIdx.x;
  const int wv = tid >> 6;       // 0..3 = N-band
  const int ln = tid & 63;
  const int l15 = ln & 15;
  const int lg = ln >> 4;
  const int rs = ln >> 3;
  const int cs = ln & 7;

  // --- block decode: XCD-aware ---
  const int ntile = p.ntx * p.nty;
  int zl, tx, ty;
  if (p.nz > 1) {
    // all tiles of one z pinned to xcd = z&7  (nz % 8 == 0, bijective)
    int xcd = bid & 7;
    int u = bid >> 3;
    zl = xcd + 8 * (u / ntile);
    int t = u % ntile;
    tx = t % p.ntx;
    ty = t / p.ntx;
  } else {
    // bijective chunked swizzle (ntile % 8 == 0)
    int xcd = bid & 7;
    int u = bid >> 3;
    int t = xcd * (ntile >> 3) + u;
    zl = 0;
    tx = t % p.ntx;
    ty = t / p.ntx;
  }
  const int zg = p.z0 + zl;
  const int bg = zg >> 2, hg = zg & 3;  // H=4
  const _Float16* A = p.A + p.sAz * zl + p.sAb * bg;
  const _Float16* Bm = p.B + p.sBz * zl + p.sBh * hg;
  const long m0 = (long)tx * 64;
  const long n0 = (long)ty * 256;
  const int nk = p.K >> 6;

  f4 acc[4][4];
#pragma unroll
  for (int i = 0; i < 4; ++i)
#pragma unroll
    for (int j = 0; j < 4; ++j) acc[i][j] = (f4)(0.0f);

  const _Float16* Ag = A + m0 * p.ldA;
  const _Float16* Bg = Bm + n0 * p.ldB;

  // --- main loop: single buffer, 2 barriers per K-step (proven structure) ---
  for (int kt = 0; kt < nk; ++kt) {
    stage_tiles5(Ag + kt * 64, Bg + kt * 64, Ash, Bsh, p.ldA, p.ldB, wv, rs, cs);
    __syncthreads();
    compute_tile5(Ash, Bsh, acc, wv, l15, lg);
    __syncthreads();
  }

  // --- epilogue: single pass through Cld [64][256] f16 (32KB) ---
  const long coff = p.sCz * zl + p.sCb * bg + p.sCh * hg;
  const float* bias = p.bias ? (p.bias + p.sBiasH * hg) : nullptr;
  _Float16* X = (EPI == 6) ? (p.aux + p.sAuxZ * zl) : nullptr;
  // transform phase: each wave fills its own 64-col band, all 64 rows
#pragma unroll
  for (int m = 0; m < 4; ++m) {
#pragma unroll
    for (int j = 0; j < 4; ++j) {
      int lrow = m * 16 + lg * 4 + j;              // 0..63
      long grow = m0 + lrow;
      int vx = (lrow & 3) << 4;                    // col-XOR within 64-band
      unsigned long long w;
      if (EPI == 2)  // wave-uniform 64-col word (cols n0+wv*64 .. +63)
        w = p.adjb[(long)bg * 16384 + grow * 16 + (n0 >> 6) + wv];
#pragma unroll
      for (int n = 0; n < 4; ++n) {
        int lcol = wv * 64 + n * 16 + l15;         // 0..255
        float v = acc[m][n][j];
        if (EPI == 5 || EPI == 6) v += bias[n0 + lcol];
        if (EPI == 2) {
          if ((w >> (n * 16 + l15)) & 1ull) {
            float ex = __expf(2.0f * v);                   // tanh = 1-2/(e^2x+1)
            v = 1.0f - 2.0f * __builtin_amdgcn_rcpf(ex + 1.0f);
          } else v = 0.0f;
        }
        if (EPI == 3) v = v > 0.0f ? v : 0.0f;
        if (EPI == 5) v = __builtin_amdgcn_rcpf(1.0f + __expf(-v));  // sigmoid
        Cld[lrow * 256 + (lcol ^ vx)] = (_Float16)v;
      }
    }
  }
  __syncthreads();
  if (EPI == 5) {
    // fused mix: out = hf*cf + ha*(1-cf); cf from Cld, hf/ha from gcat(=aux)
    float* C = (float*)p.C;
    const _Float16* gcat = (const _Float16*)p.aux;
#pragma unroll
    for (int it = 0; it < 8; ++it) {
      int row = it * 8 + (tid >> 5);               // 0..63
      int col0 = (tid & 31) * 8;                   // 0..248
      int vx = (row & 3) << 4;
      h8 cf = *(const h8*)&Cld[row * 256 + (col0 ^ vx)];
      long grow = m0 + row;
      long gc = n0 + col0;
      h8 hf = *(const h8*)&gcat[grow * 1024 + gc];
      h8 ha = *(const h8*)&gcat[grow * 1024 + 512 + gc];
      float o[8];
#pragma unroll
      for (int j = 0; j < 8; ++j) {
        float c = (float)cf[j];
        o[j] = (float)hf[j] * c + (float)ha[j] * (1.0f - c);
      }
      float* op = &C[grow * p.ldC + gc];
      *(float4*)op = make_float4(o[0], o[1], o[2], o[3]);
      *(float4*)(op + 4) = make_float4(o[4], o[5], o[6], o[7]);
    }
  } else {
    // store phase: 64x256 f16, all 256 threads
    _Float16* C = (_Float16*)p.C;
#pragma unroll
    for (int it = 0; it < 8; ++it) {
      int row = it * 8 + (tid >> 5);               // 0..63
      int col0 = (tid & 31) * 8;                   // 0..248
      int vx = (row & 3) << 4;
      h8 o = *(const h8*)&Cld[row * 256 + (col0 ^ vx)];
      *(h8*)&C[coff + (m0 + row) * p.ldC + n0 + col0] = o;
    }
    if (EPI == 6) {
      // dual store: aux[col][row] = C-tile^T  (WhT [512][1024] per z)
#pragma unroll
      for (int it = 0; it < 8; ++it) {
        int idx = it * 256 + tid;                  // 0..2047
        int ol = idx >> 3;                         // tile col 0..255
        int ml = (idx & 7) * 8;                    // row block 0..56
        h8 o;
#pragma unroll
        for (int j = 0; j < 8; ++j) {
          int mm = ml + j;
          o[j] = Cld[mm * 256 + (ol ^ ((mm & 3) << 4))];
        }
        *(h8*)&X[(n0 + ol) * 1024 + m0 + ml] = o;
      }
    }
  }
}

#define GEMM_WRAP(name, epi) \
  __global__ __launch_bounds__(256) void name(GP p) { gemm_core<epi>(p, blockIdx.x); }
GEMM_WRAP(gemm_wh, 6)
GEMM_WRAP(gemm_e, 0)
GEMM_WRAP(gemm_amat, 2)
GEMM_WRAP(gemm_cat, 3)
GEMM_WRAP(gemm_gate, 5)

// merged independent tail GEMMs: blocks [0,512) = hf, [512,1024) = ha
__global__ __launch_bounds__(256) void gemm_hfha(GP a, GP b) {
  if (blockIdx.x < 512) gemm_core<0>(a, blockIdx.x);
  else                  gemm_core<0>(b, blockIdx.x - 512);
}

// ---------------------------------------------------------------------------
// prep_main: all prep in ONE launch (segment decode by block).
//   [0, 65536)        adj bitmask (fmt re-derived locally from adj[0:4096])
//   [65536, 73728)    h fp32 -> f16 (2M float4)
//   [73728, 74752)    W cvt (256K float4)
//   [74752, 75776)    A_w cvt
//   [75776, 76032)    fc cvt (64K float4)
//   [76032, 78080)    gw = [g1|g2] f16 (512K elems)
//   [78080, 78336)    attn transpose: 256 tiles of 64x64 (LDS)
// ---------------------------------------------------------------------------
struct PREP {
  const void* adj; unsigned long long* adjb;
  const float* h; _Float16* h16;
  const float* W; _Float16* W16;
  const float* Aw; _Float16* Aw16;
  const float* fc; _Float16* fc16;
  const float* g1; const float* g2; _Float16* gw16;
  const float* attn; _Float16* attnT;
};

__global__ __launch_bounds__(256) void prep_main(PREP pp) {
  __shared__ _Float16 tl[64][65];
  __shared__ int sf[3];
  const int bid = blockIdx.x;
  const int tid = threadIdx.x;
  if (bid < 65536) {
    // local fmt detection from first 4KB (L2-broadcast read, branch-uniform)
    if (tid < 3) sf[tid] = 0;
    __syncthreads();
    const unsigned char* ab = (const unsigned char*)pp.adj;
    int a = 0, b = 0, c = 0;
    for (int i = tid; i < 4096; i += 256) {
      if (ab[i]) {
        if (i & 3) a = 1;
        else c = 1;
        if ((i & 7) == 4) b = 1;
      }
    }
    if (a) sf[0] = 1;
    if (b) sf[1] = 1;
    if (c) sf[2] = 1;
    __syncthreads();
    int fmt;
    if (sf[0]) fmt = sf[2] ? 1 : 3;   // bool bytes vs float32
    else       fmt = sf[1] ? 0 : 2;   // int32 vs int64
    long i = (long)bid * 256 + tid;   // 16,777,216 elements
    bool v;
    if (fmt == 1) v = ((const unsigned char*)pp.adj)[i] != 0;
    else if (fmt == 3) v = ((const float*)pp.adj)[i] != 0.0f;
    else if (fmt == 2) v = ((const long long*)pp.adj)[i] != 0;
    else v = ((const int*)pp.adj)[i] != 0;
    unsigned long long m = __ballot(v);
    if ((tid & 63) == 0) pp.adjb[i >> 6] = m;
  } else if (bid < 73728) {
    int i = (bid - 65536) * 256 + tid;         // h: 2,097,152 float4
    float4 v = ((const float4*)pp.h)[i];
    h4 o = {(_Float16)v.x, (_Float16)v.y, (_Float16)v.z, (_Float16)v.w};
    ((h4*)pp.h16)[i] = o;
  } else if (bid < 74752) {
    int i = (bid - 73728) * 256 + tid;         // W: 262,144 float4
    float4 v = ((const float4*)pp.W)[i];
    h4 o = {(_Float16)v.x, (_Float16)v.y, (_Float16)v.z, (_Float16)v.w};
    ((h4*)pp.W16)[i] = o;
  } else if (bid < 75776) {
    int i = (bid - 74752) * 256 + tid;         // A_w: 262,144 float4
    float4 v = ((const float4*)pp.Aw)[i];
    h4 o = {(_Float16)v.x, (_Float16)v.y, (_Float16)v.z, (_Float16)v.w};
    ((h4*)pp.Aw16)[i] = o;
  } else if (bid < 76032) {
    int i = (bid - 75776) * 256 + tid;         // fc: 65,536 float4
    float4 v = ((const float4*)pp.fc)[i];
    h4 o = {(_Float16)v.x, (_Float16)v.y, (_Float16)v.z, (_Float16)v.w};
    ((h4*)pp.fc16)[i] = o;
  } else if (bid < 78080) {
    int i = (bid - 76032) * 256 + tid;         // gw: 524,288 elems
    int o = i >> 10, k = i & 1023;
    float v = (k < 512) ? pp.g1[o * 512 + k] : pp.g2[o * 512 + (k - 512)];
    pp.gw16[i] = (_Float16)v;
  } else {
    int t = bid - 78080;                       // attn transpose, 256 tiles
    const long hh = t >> 6;
    const int rem = t & 63;
    const int r0 = (rem >> 3) * 64, c0 = (rem & 7) * 64;
    const float* I = pp.attn + hh * 262144;
    _Float16* O = pp.attnT + hh * 262144;
    for (int i = tid; i < 4096; i += 256) {
      int r = i >> 6, c = i & 63;
      tl[c][r] = (_Float16)I[(long)(r0 + r) * 512 + c0 + c];
    }
    __syncthreads();
    for (int i = tid; i < 4096; i += 256) {
      int c = i >> 6, r = i & 63;
      O[(long)(c0 + c) * 512 + r0 + r] = tl[c][r];
    }
  }
}

extern "C" void kernel_launch(void* const* d_in, const int* in_sizes, int n_in,
                              void* d_out, int out_size, void* d_ws, size_t ws_size,
                              hipStream_t stream) {
  const float* h    = (const float*)d_in[0];
  const void*  adj  = d_in[1];
  const float* W    = (const float*)d_in[2];
  const float* bW   = (const float*)d_in[3];
  const float* attn = (const float*)d_in[4];
  const float* A_w  = (const float*)d_in[5];
  const float* fc_w = (const float*)d_in[6];
  const float* g1   = (const float*)d_in[7];
  const float* g2   = (const float*)d_in[8];
  const float* gbias= (const float*)d_in[9];
  float* out = (float*)d_out;
  char* ws = (char*)d_ws;
  (void)in_sizes; (void)n_in; (void)out_size;

  // --- exact-fit chunk sizing ---
  const size_t MB = 1ull << 20;
  const size_t fixedB = 92 * MB;           // fixed buffers (~89.8MB) + slack
  int ZCv = 16;
  if (fixedB + 5ull * 64 * MB <= ws_size) ZCv = 64;
  else if (fixedB + 5ull * 32 * MB <= ws_size) ZCv = 32;
  const int nchunk = 64 / ZCv;

  size_t off = 0;
  auto alloc = [&](size_t sz) { size_t o = off; off += (sz + 255) & ~(size_t)255; return o; };
  const size_t oFlags = alloc(256);
  const size_t oH16   = alloc(16 * MB);
  const size_t oW16   = alloc(2 * MB);
  const size_t oAttnT = alloc(2 * MB);
  const size_t oAw16  = alloc(2 * MB);
  const size_t oFc16  = alloc(512 * 1024);
  const size_t oGw16  = alloc(1 * MB);
  const size_t oAdjb  = alloc(2 * MB);
  const size_t oCat   = alloc(64 * MB);
  const size_t oWhC   = alloc((size_t)ZCv * MB);       // Wh chunk f16 [ZC][1024][512]
  const size_t oEC    = alloc((size_t)ZCv * MB);       // e chunk (contiguous after WhC)
  const size_t oWhTC  = alloc((size_t)ZCv * MB);       // WhT chunk f16 [ZC][512][1024]
  const size_t oAmatC = alloc((size_t)ZCv * 2 * MB);   // Amat chunk f16 [ZC][1024][1024]
  const size_t oGcat  = oWhC;    // gcat f16 [16384][1024] (32MB <= WhC+EC)
  (void)oFlags;

  _Float16* h16   = (_Float16*)(ws + oH16);
  _Float16* W16   = (_Float16*)(ws + oW16);
  _Float16* attnT = (_Float16*)(ws + oAttnT);
  _Float16* Aw16  = (_Float16*)(ws + oAw16);
  _Float16* fc16  = (_Float16*)(ws + oFc16);
  _Float16* gw16  = (_Float16*)(ws + oGw16);
  unsigned long long* adjb = (unsigned long long*)(ws + oAdjb);
  _Float16* cat   = (_Float16*)(ws + oCat);
  _Float16* WhC   = (_Float16*)(ws + oWhC);
  _Float16* eC    = (_Float16*)(ws + oEC);
  _Float16* WhTC  = (_Float16*)(ws + oWhTC);
  _Float16* AmatC = (_Float16*)(ws + oAmatC);
  _Float16* gcat  = (_Float16*)(ws + oGcat);

  // --- prep: 1 launch ---
  PREP pp;
  pp.adj = adj; pp.adjb = adjb;
  pp.h = h; pp.h16 = h16;
  pp.W = W; pp.W16 = W16;
  pp.Aw = A_w; pp.Aw16 = Aw16;
  pp.fc = fc_w; pp.fc16 = fc16;
  pp.g1 = g1; pp.g2 = g2; pp.gw16 = gw16;
  pp.attn = attn; pp.attnT = attnT;
  prep_main<<<78336, 256, 0, stream>>>(pp);

  // --- heavy pipeline (per chunk) ---
  for (int c = 0; c < nchunk; ++c) {
    const int z0 = c * ZCv;
    GP q;
    // Wh = h*W^T + bW  (+ WhT dual store)
    q = GP{};
    q.A = h16; q.B = W16; q.C = WhC; q.bias = bW; q.aux = WhTC;
    q.K = 512; q.ldA = 512; q.ldB = 512; q.ldC = 512; q.z0 = z0;
    q.ntx = 16; q.nty = 2; q.nz = ZCv;
    q.sAz = 0; q.sAb = 524288; q.sBz = 0; q.sBh = 262144;
    q.sCz = 524288; q.sCb = 0; q.sCh = 0; q.sBiasH = 512; q.sAuxZ = 524288;
    gemm_wh<<<32 * ZCv, 256, 0, stream>>>(q);
    // e = Wh*attn
    q = GP{};
    q.A = WhC; q.B = attnT; q.C = eC;
    q.K = 512; q.ldA = 512; q.ldB = 512; q.ldC = 512; q.z0 = z0;
    q.ntx = 16; q.nty = 2; q.nz = ZCv;
    q.sAz = 524288; q.sBh = 262144; q.sCz = 524288;
    gemm_e<<<32 * ZCv, 256, 0, stream>>>(q);
    // Amat = tanh(mask(e*Wh^T))
    q = GP{};
    q.A = eC; q.B = WhC; q.C = AmatC; q.adjb = adjb;
    q.K = 512; q.ldA = 512; q.ldB = 512; q.ldC = 1024; q.z0 = z0;
    q.ntx = 16; q.nty = 4; q.nz = ZCv;
    q.sAz = 524288; q.sBz = 524288; q.sCz = 1048576;
    gemm_amat<<<64 * ZCv, 256, 0, stream>>>(q);
    // cat[b][n][h*512+o] = relu(Amat*WhT^T)
    q = GP{};
    q.A = AmatC; q.B = WhTC; q.C = cat;
    q.K = 1024; q.ldA = 1024; q.ldB = 1024; q.ldC = 2048; q.z0 = z0;
    q.sAz = 1048576; q.sBz = 524288;
    q.ntx = 16; q.nty = 2; q.nz = ZCv;
    q.sCz = 0; q.sCb = 2097152; q.sCh = 512;
    gemm_cat<<<32 * ZCv, 256, 0, stream>>>(q);
  }

  // --- tail ---
  GP qa, qb, q;
  // hf = h*fc^T -> gcat[:,0:512]
  qa = GP{};
  qa.A = h16; qa.B = fc16; qa.C = gcat;
  qa.K = 512; qa.ldA = 512; qa.ldB = 512; qa.ldC = 1024; qa.z0 = 0;
  qa.ntx = 256; qa.nty = 2; qa.nz = 1;
  // ha = cat*A_w^T -> gcat[:,512:1024]
  qb = GP{};
  qb.A = cat; qb.B = Aw16; qb.C = gcat + 512;
  qb.K = 2048; qb.ldA = 2048; qb.ldB = 2048; qb.ldC = 1024; qb.z0 = 0;
  qb.ntx = 256; qb.nty = 2; qb.nz = 1;
  gemm_hfha<<<1024, 256, 0, stream>>>(qa, qb);
  // out = hf*sig(gcat*[g1|g2]^T + gbias) + ha*(1-sig(...))  (fused gate+mix)
  q = GP{};
  q.A = gcat; q.B = gw16; q.C = out; q.bias = gbias; q.aux = gcat;
  q.K = 1024; q.ldA = 1024; q.ldB = 1024; q.ldC = 512; q.z0 = 0;
  q.ntx = 256; q.nty = 2; q.nz = 1; q.sBiasH = 0;
  gemm_gate<<<512, 256, 0, stream>>>(q);
}

// Round 20
// 476.041 us; speedup vs baseline: 1.2115x; 1.2115x over previous
//
#include <hip/hip_runtime.h>
#include <hip/hip_fp16.h>

// ---------------------------------------------------------------------------
// GraphAttention on MI355X (gfx950). f16 MFMA, fp32 accum.
// R20 = R18 (best: 474.6 us) + R19's hf/ha merge ONLY.
// R19's detect_fmt fold REVERTED: folding the 4KB format probe into all
// 65536 adj blocks cost 16 redundant scan iterations per block ->
// prep_main 176 us (was ~75). Separate 1-block detect_fmt restored;
// prep_main reads the flag. gemm_hfha merge kept (independent tail GEMMs
// in one dispatch). 12 dispatches total.
// GEMM core byte-identical to R18: 64x256 tile, 4 waves, per-wave 64x64
// acc[4][4], single-buffer 2-barrier loop, 40KB LDS, z->XCD pinning,
// fused epilogues (bias/mask+tanh/relu/WhT dual-store/gate+mix).
// ---------------------------------------------------------------------------

typedef _Float16 h8 __attribute__((ext_vector_type(8)));
typedef _Float16 h4 __attribute__((ext_vector_type(4)));
typedef float f4 __attribute__((ext_vector_type(4)));

__device__ __forceinline__ void load_lds16(const void* g, void* l) {
  __builtin_amdgcn_global_load_lds(
      (const __attribute__((address_space(1))) unsigned int*)g,
      (__attribute__((address_space(3))) unsigned int*)l, 16, 0, 0);
}

struct GP {
  const _Float16* A; const _Float16* B; void* C; const float* bias;
  const unsigned long long* adjb; _Float16* aux;
  int K, ldA, ldB, ldC, z0, ntx, nty, nz;
  long sAz, sAb, sBz, sBh, sCz, sCb, sCh, sBiasH, sAuxZ;
};

// Stage A (64x64, chunks 0..7) and B (256x64, chunks 8..39) into LDS.
// Element (row,k) lives at byte row*128 + ((2k) ^ ((row&7)<<4)).
__device__ __forceinline__ void stage_tiles5(const _Float16* Ag, const _Float16* Bg,
                                             _Float16* As, _Float16* Bs,
                                             int ldA, int ldB, int wv, int rs, int cs) {
#pragma unroll
  for (int ps = 0; ps < 10; ++ps) {
    int c = ps * 4 + wv;            // 0..39, wave-uniform
    if (c < 8) {
      int r = c * 8 + rs;           // A row 0..63
      int kb = (cs ^ (r & 7)) * 8;
      load_lds16(Ag + (long)r * ldA + kb, As + c * 512);
    } else {
      int cb = c - 8;
      int r = cb * 8 + rs;          // B row 0..255
      int kb = (cs ^ (r & 7)) * 8;
      load_lds16(Bg + (long)r * ldB + kb, Bs + cb * 512);
    }
  }
}

__device__ __forceinline__ void compute_tile5(const _Float16* As, const _Float16* Bs,
                                              f4 acc[4][4], int wv, int l15, int lg) {
#pragma unroll
  for (int ks = 0; ks < 2; ++ks) {
    const int kby = ks * 64 + lg * 16;
    h8 av[4], bv[4];
#pragma unroll
    for (int m = 0; m < 4; ++m) {
      int row = m * 16 + l15;                       // 0..63
      av[m] = *(const h8*)((const char*)As + row * 128 + (kby ^ ((row & 7) << 4)));
    }
#pragma unroll
    for (int n = 0; n < 4; ++n) {
      int col = wv * 64 + n * 16 + l15;             // 0..255
      bv[n] = *(const h8*)((const char*)Bs + col * 128 + (kby ^ ((col & 7) << 4)));
    }
#pragma unroll
    for (int m = 0; m < 4; ++m)
#pragma unroll
      for (int n = 0; n < 4; ++n)
        acc[m][n] = __builtin_amdgcn_mfma_f32_16x16x32_f16(av[m], bv[n], acc[m][n], 0, 0, 0);
  }
}

// BT-GEMM body: C[M,N] = A[M,K]*B[N,K]^T, 64x256 tile, BK=64, 4 waves
// (1M x 4N, per-wave 64x64), single-buffered 40KB LDS, 2 barriers/K-step,
// 1D XCD-aware decode on explicit bid, single-pass f16-LDS epilogue.
// EPI: 0 f16 | 2 mask+tanh f16 | 3 relu f16
//      | 5 bias+sigmoid, fused mix (reads aux=gcat, writes fp32 out)
//      | 6 bias f16 + dual store (C and aux=C^T)
template<int EPI>
__device__ __forceinline__ void gemm_core(GP p, int bid) {
  __shared__ __align__(16) char smem[40960];
  _Float16* Ash = (_Float16*)smem;                    // [64*64] f16, 8KB
  _Float16* Bsh = (_Float16*)(smem + 8192);           // [256*64] f16, 32KB
  _Float16* Cld = (_Float16*)smem;                    // epilogue alias, 32KB

  const int tid = threadIdx.x;
  const int wv = tid >> 6;       // 0..3 = N-band
  const int ln = tid & 63;
  const int l15 = ln & 15;
  const int lg = ln >> 4;
  const int rs = ln >> 3;
  const int cs = ln & 7;

  // --- block decode: XCD-aware ---
  const int ntile = p.ntx * p.nty;
  int zl, tx, ty;
  if (p.nz > 1) {
    // all tiles of one z pinned to xcd = z&7  (nz % 8 == 0, bijective)
    int xcd = bid & 7;
    int u = bid >> 3;
    zl = xcd + 8 * (u / ntile);
    int t = u % ntile;
    tx = t % p.ntx;
    ty = t / p.ntx;
  } else {
    // bijective chunked swizzle (ntile % 8 == 0)
    int xcd = bid & 7;
    int u = bid >> 3;
    int t = xcd * (ntile >> 3) + u;
    zl = 0;
    tx = t % p.ntx;
    ty = t / p.ntx;
  }
  const int zg = p.z0 + zl;
  const int bg = zg >> 2, hg = zg & 3;  // H=4
  const _Float16* A = p.A + p.sAz * zl + p.sAb * bg;
  const _Float16* Bm = p.B + p.sBz * zl + p.sBh * hg;
  const long m0 = (long)tx * 64;
  const long n0 = (long)ty * 256;
  const int nk = p.K >> 6;

  f4 acc[4][4];
#pragma unroll
  for (int i = 0; i < 4; ++i)
#pragma unroll
    for (int j = 0; j < 4; ++j) acc[i][j] = (f4)(0.0f);

  const _Float16* Ag = A + m0 * p.ldA;
  const _Float16* Bg = Bm + n0 * p.ldB;

  // --- main loop: single buffer, 2 barriers per K-step (proven structure) ---
  for (int kt = 0; kt < nk; ++kt) {
    stage_tiles5(Ag + kt * 64, Bg + kt * 64, Ash, Bsh, p.ldA, p.ldB, wv, rs, cs);
    __syncthreads();
    compute_tile5(Ash, Bsh, acc, wv, l15, lg);
    __syncthreads();
  }

  // --- epilogue: single pass through Cld [64][256] f16 (32KB) ---
  const long coff = p.sCz * zl + p.sCb * bg + p.sCh * hg;
  const float* bias = p.bias ? (p.bias + p.sBiasH * hg) : nullptr;
  _Float16* X = (EPI == 6) ? (p.aux + p.sAuxZ * zl) : nullptr;
  // transform phase: each wave fills its own 64-col band, all 64 rows
#pragma unroll
  for (int m = 0; m < 4; ++m) {
#pragma unroll
    for (int j = 0; j < 4; ++j) {
      int lrow = m * 16 + lg * 4 + j;              // 0..63
      long grow = m0 + lrow;
      int vx = (lrow & 3) << 4;                    // col-XOR within 64-band
      unsigned long long w;
      if (EPI == 2)  // wave-uniform 64-col word (cols n0+wv*64 .. +63)
        w = p.adjb[(long)bg * 16384 + grow * 16 + (n0 >> 6) + wv];
#pragma unroll
      for (int n = 0; n < 4; ++n) {
        int lcol = wv * 64 + n * 16 + l15;         // 0..255
        float v = acc[m][n][j];
        if (EPI == 5 || EPI == 6) v += bias[n0 + lcol];
        if (EPI == 2) {
          if ((w >> (n * 16 + l15)) & 1ull) {
            float ex = __expf(2.0f * v);                   // tanh = 1-2/(e^2x+1)
            v = 1.0f - 2.0f * __builtin_amdgcn_rcpf(ex + 1.0f);
          } else v = 0.0f;
        }
        if (EPI == 3) v = v > 0.0f ? v : 0.0f;
        if (EPI == 5) v = __builtin_amdgcn_rcpf(1.0f + __expf(-v));  // sigmoid
        Cld[lrow * 256 + (lcol ^ vx)] = (_Float16)v;
      }
    }
  }
  __syncthreads();
  if (EPI == 5) {
    // fused mix: out = hf*cf + ha*(1-cf); cf from Cld, hf/ha from gcat(=aux)
    float* C = (float*)p.C;
    const _Float16* gcat = (const _Float16*)p.aux;
#pragma unroll
    for (int it = 0; it < 8; ++it) {
      int row = it * 8 + (tid >> 5);               // 0..63
      int col0 = (tid & 31) * 8;                   // 0..248
      int vx = (row & 3) << 4;
      h8 cf = *(const h8*)&Cld[row * 256 + (col0 ^ vx)];
      long grow = m0 + row;
      long gc = n0 + col0;
      h8 hf = *(const h8*)&gcat[grow * 1024 + gc];
      h8 ha = *(const h8*)&gcat[grow * 1024 + 512 + gc];
      float o[8];
#pragma unroll
      for (int j = 0; j < 8; ++j) {
        float c = (float)cf[j];
        o[j] = (float)hf[j] * c + (float)ha[j] * (1.0f - c);
      }
      float* op = &C[grow * p.ldC + gc];
      *(float4*)op = make_float4(o[0], o[1], o[2], o[3]);
      *(float4*)(op + 4) = make_float4(o[4], o[5], o[6], o[7]);
    }
  } else {
    // store phase: 64x256 f16, all 256 threads
    _Float16* C = (_Float16*)p.C;
#pragma unroll
    for (int it = 0; it < 8; ++it) {
      int row = it * 8 + (tid >> 5);               // 0..63
      int col0 = (tid & 31) * 8;                   // 0..248
      int vx = (row & 3) << 4;
      h8 o = *(const h8*)&Cld[row * 256 + (col0 ^ vx)];
      *(h8*)&C[coff + (m0 + row) * p.ldC + n0 + col0] = o;
    }
    if (EPI == 6) {
      // dual store: aux[col][row] = C-tile^T  (WhT [512][1024] per z)
#pragma unroll
      for (int it = 0; it < 8; ++it) {
        int idx = it * 256 + tid;                  // 0..2047
        int ol = idx >> 3;                         // tile col 0..255
        int ml = (idx & 7) * 8;                    // row block 0..56
        h8 o;
#pragma unroll
        for (int j = 0; j < 8; ++j) {
          int mm = ml + j;
          o[j] = Cld[mm * 256 + (ol ^ ((mm & 3) << 4))];
        }
        *(h8*)&X[(n0 + ol) * 1024 + m0 + ml] = o;
      }
    }
  }
}

#define GEMM_WRAP(name, epi) \
  __global__ __launch_bounds__(256) void name(GP p) { gemm_core<epi>(p, blockIdx.x); }
GEMM_WRAP(gemm_wh, 6)
GEMM_WRAP(gemm_e, 0)
GEMM_WRAP(gemm_amat, 2)
GEMM_WRAP(gemm_cat, 3)
GEMM_WRAP(gemm_gate, 5)

// merged independent tail GEMMs: blocks [0,512) = hf, [512,1024) = ha
__global__ __launch_bounds__(256) void gemm_hfha(GP a, GP b) {
  if (blockIdx.x < 512) gemm_core<0>(a, blockIdx.x);
  else                  gemm_core<0>(b, blockIdx.x - 512);
}

// Probe adj element format. fmt: 0=int32, 1=byte/bool, 2=int64, 3=float32
__global__ void detect_fmt(const unsigned char* adj, int* flags) {
  __shared__ int sa, sb, sc;
  if (threadIdx.x == 0) { sa = 0; sb = 0; sc = 0; }
  __syncthreads();
  int a = 0, b = 0, c = 0;
  for (int i = threadIdx.x; i < 4096; i += 256) {
    if (adj[i]) {
      if (i & 3) a = 1;
      else c = 1;
      if ((i & 7) == 4) b = 1;
    }
  }
  if (a) sa = 1;
  if (b) sb = 1;
  if (c) sc = 1;
  __syncthreads();
  if (threadIdx.x == 0) {
    int fmt;
    if (sa) fmt = sc ? 1 : 3;
    else fmt = sb ? 0 : 2;
    flags[0] = fmt;
  }
}

// ---------------------------------------------------------------------------
// prep_main: all data-parallel prep in ONE launch (segment decode by block).
//   [0, 65536)        adj bitmask (fmt from flags, set by detect_fmt)
//   [65536, 73728)    h fp32 -> f16 (2M float4)
//   [73728, 74752)    W cvt (256K float4)
//   [74752, 75776)    A_w cvt
//   [75776, 76032)    fc cvt (64K float4)
//   [76032, 78080)    gw = [g1|g2] f16 (512K elems)
//   [78080, 78336)    attn transpose: 256 tiles of 64x64 (LDS)
// ---------------------------------------------------------------------------
struct PREP {
  const void* adj; const int* flags; unsigned long long* adjb;
  const float* h; _Float16* h16;
  const float* W; _Float16* W16;
  const float* Aw; _Float16* Aw16;
  const float* fc; _Float16* fc16;
  const float* g1; const float* g2; _Float16* gw16;
  const float* attn; _Float16* attnT;
};

__global__ __launch_bounds__(256) void prep_main(PREP pp) {
  __shared__ _Float16 tl[64][65];
  const int bid = blockIdx.x;
  const int tid = threadIdx.x;
  if (bid < 65536) {
    long i = (long)bid * 256 + tid;            // 16,777,216 elements
    int fmt = pp.flags[0];
    bool v;
    if (fmt == 1) v = ((const unsigned char*)pp.adj)[i] != 0;
    else if (fmt == 3) v = ((const float*)pp.adj)[i] != 0.0f;
    else if (fmt == 2) v = ((const long long*)pp.adj)[i] != 0;
    else v = ((const int*)pp.adj)[i] != 0;
    unsigned long long m = __ballot(v);
    if ((tid & 63) == 0) pp.adjb[i >> 6] = m;
  } else if (bid < 73728) {
    int i = (bid - 65536) * 256 + tid;         // h: 2,097,152 float4
    float4 v = ((const float4*)pp.h)[i];
    h4 o = {(_Float16)v.x, (_Float16)v.y, (_Float16)v.z, (_Float16)v.w};
    ((h4*)pp.h16)[i] = o;
  } else if (bid < 74752) {
    int i = (bid - 73728) * 256 + tid;         // W: 262,144 float4
    float4 v = ((const float4*)pp.W)[i];
    h4 o = {(_Float16)v.x, (_Float16)v.y, (_Float16)v.z, (_Float16)v.w};
    ((h4*)pp.W16)[i] = o;
  } else if (bid < 75776) {
    int i = (bid - 74752) * 256 + tid;         // A_w: 262,144 float4
    float4 v = ((const float4*)pp.Aw)[i];
    h4 o = {(_Float16)v.x, (_Float16)v.y, (_Float16)v.z, (_Float16)v.w};
    ((h4*)pp.Aw16)[i] = o;
  } else if (bid < 76032) {
    int i = (bid - 75776) * 256 + tid;         // fc: 65,536 float4
    float4 v = ((const float4*)pp.fc)[i];
    h4 o = {(_Float16)v.x, (_Float16)v.y, (_Float16)v.z, (_Float16)v.w};
    ((h4*)pp.fc16)[i] = o;
  } else if (bid < 78080) {
    int i = (bid - 76032) * 256 + tid;         // gw: 524,288 elems
    int o = i >> 10, k = i & 1023;
    float v = (k < 512) ? pp.g1[o * 512 + k] : pp.g2[o * 512 + (k - 512)];
    pp.gw16[i] = (_Float16)v;
  } else {
    int t = bid - 78080;                       // attn transpose, 256 tiles
    const long hh = t >> 6;
    const int rem = t & 63;
    const int r0 = (rem >> 3) * 64, c0 = (rem & 7) * 64;
    const float* I = pp.attn + hh * 262144;
    _Float16* O = pp.attnT + hh * 262144;
    for (int i = tid; i < 4096; i += 256) {
      int r = i >> 6, c = i & 63;
      tl[c][r] = (_Float16)I[(long)(r0 + r) * 512 + c0 + c];
    }
    __syncthreads();
    for (int i = tid; i < 4096; i += 256) {
      int c = i >> 6, r = i & 63;
      O[(long)(c0 + c) * 512 + r0 + r] = tl[c][r];
    }
  }
}

extern "C" void kernel_launch(void* const* d_in, const int* in_sizes, int n_in,
                              void* d_out, int out_size, void* d_ws, size_t ws_size,
                              hipStream_t stream) {
  const float* h    = (const float*)d_in[0];
  const void*  adj  = d_in[1];
  const float* W    = (const float*)d_in[2];
  const float* bW   = (const float*)d_in[3];
  const float* attn = (const float*)d_in[4];
  const float* A_w  = (const float*)d_in[5];
  const float* fc_w = (const float*)d_in[6];
  const float* g1   = (const float*)d_in[7];
  const float* g2   = (const float*)d_in[8];
  const float* gbias= (const float*)d_in[9];
  float* out = (float*)d_out;
  char* ws = (char*)d_ws;
  (void)in_sizes; (void)n_in; (void)out_size;

  // --- exact-fit chunk sizing ---
  const size_t MB = 1ull << 20;
  const size_t fixedB = 92 * MB;           // fixed buffers (~89.8MB) + slack
  int ZCv = 16;
  if (fixedB + 5ull * 64 * MB <= ws_size) ZCv = 64;
  else if (fixedB + 5ull * 32 * MB <= ws_size) ZCv = 32;
  const int nchunk = 64 / ZCv;

  size_t off = 0;
  auto alloc = [&](size_t sz) { size_t o = off; off += (sz + 255) & ~(size_t)255; return o; };
  const size_t oFlags = alloc(256);
  const size_t oH16   = alloc(16 * MB);
  const size_t oW16   = alloc(2 * MB);
  const size_t oAttnT = alloc(2 * MB);
  const size_t oAw16  = alloc(2 * MB);
  const size_t oFc16  = alloc(512 * 1024);
  const size_t oGw16  = alloc(1 * MB);
  const size_t oAdjb  = alloc(2 * MB);
  const size_t oCat   = alloc(64 * MB);
  const size_t oWhC   = alloc((size_t)ZCv * MB);       // Wh chunk f16 [ZC][1024][512]
  const size_t oEC    = alloc((size_t)ZCv * MB);       // e chunk (contiguous after WhC)
  const size_t oWhTC  = alloc((size_t)ZCv * MB);       // WhT chunk f16 [ZC][512][1024]
  const size_t oAmatC = alloc((size_t)ZCv * 2 * MB);   // Amat chunk f16 [ZC][1024][1024]
  const size_t oGcat  = oWhC;    // gcat f16 [16384][1024] (32MB <= WhC+EC)

  int* flags = (int*)(ws + oFlags);
  _Float16* h16   = (_Float16*)(ws + oH16);
  _Float16* W16   = (_Float16*)(ws + oW16);
  _Float16* attnT = (_Float16*)(ws + oAttnT);
  _Float16* Aw16  = (_Float16*)(ws + oAw16);
  _Float16* fc16  = (_Float16*)(ws + oFc16);
  _Float16* gw16  = (_Float16*)(ws + oGw16);
  unsigned long long* adjb = (unsigned long long*)(ws + oAdjb);
  _Float16* cat   = (_Float16*)(ws + oCat);
  _Float16* WhC   = (_Float16*)(ws + oWhC);
  _Float16* eC    = (_Float16*)(ws + oEC);
  _Float16* WhTC  = (_Float16*)(ws + oWhTC);
  _Float16* AmatC = (_Float16*)(ws + oAmatC);
  _Float16* gcat  = (_Float16*)(ws + oGcat);

  // --- prep: 2 launches ---
  detect_fmt<<<1, 256, 0, stream>>>((const unsigned char*)adj, flags);
  PREP pp;
  pp.adj = adj; pp.flags = flags; pp.adjb = adjb;
  pp.h = h; pp.h16 = h16;
  pp.W = W; pp.W16 = W16;
  pp.Aw = A_w; pp.Aw16 = Aw16;
  pp.fc = fc_w; pp.fc16 = fc16;
  pp.g1 = g1; pp.g2 = g2; pp.gw16 = gw16;
  pp.attn = attn; pp.attnT = attnT;
  prep_main<<<78336, 256, 0, stream>>>(pp);

  // --- heavy pipeline (per chunk) ---
  for (int c = 0; c < nchunk; ++c) {
    const int z0 = c * ZCv;
    GP q;
    // Wh = h*W^T + bW  (+ WhT dual store)
    q = GP{};
    q.A = h16; q.B = W16; q.C = WhC; q.bias = bW; q.aux = WhTC;
    q.K = 512; q.ldA = 512; q.ldB = 512; q.ldC = 512; q.z0 = z0;
    q.ntx = 16; q.nty = 2; q.nz = ZCv;
    q.sAz = 0; q.sAb = 524288; q.sBz = 0; q.sBh = 262144;
    q.sCz = 524288; q.sCb = 0; q.sCh = 0; q.sBiasH = 512; q.sAuxZ = 524288;
    gemm_wh<<<32 * ZCv, 256, 0, stream>>>(q);
    // e = Wh*attn
    q = GP{};
    q.A = WhC; q.B = attnT; q.C = eC;
    q.K = 512; q.ldA = 512; q.ldB = 512; q.ldC = 512; q.z0 = z0;
    q.ntx = 16; q.nty = 2; q.nz = ZCv;
    q.sAz = 524288; q.sBh = 262144; q.sCz = 524288;
    gemm_e<<<32 * ZCv, 256, 0, stream>>>(q);
    // Amat = tanh(mask(e*Wh^T))
    q = GP{};
    q.A = eC; q.B = WhC; q.C = AmatC; q.adjb = adjb;
    q.K = 512; q.ldA = 512; q.ldB = 512; q.ldC = 1024; q.z0 = z0;
    q.ntx = 16; q.nty = 4; q.nz = ZCv;
    q.sAz = 524288; q.sBz = 524288; q.sCz = 1048576;
    gemm_amat<<<64 * ZCv, 256, 0, stream>>>(q);
    // cat[b][n][h*512+o] = relu(Amat*WhT^T)
    q = GP{};
    q.A = AmatC; q.B = WhTC; q.C = cat;
    q.K = 1024; q.ldA = 1024; q.ldB = 1024; q.ldC = 2048; q.z0 = z0;
    q.sAz = 1048576; q.sBz = 524288;
    q.ntx = 16; q.nty = 2; q.nz = ZCv;
    q.sCz = 0; q.sCb = 2097152; q.sCh = 512;
    gemm_cat<<<32 * ZCv, 256, 0, stream>>>(q);
  }

  // --- tail ---
  GP qa, qb, q;
  // hf = h*fc^T -> gcat[:,0:512]
  qa = GP{};
  qa.A = h16; qa.B = fc16; qa.C = gcat;
  qa.K = 512; qa.ldA = 512; qa.ldB = 512; qa.ldC = 1024; qa.z0 = 0;
  qa.ntx = 256; qa.nty = 2; qa.nz = 1;
  // ha = cat*A_w^T -> gcat[:,512:1024]
  qb = GP{};
  qb.A = cat; qb.B = Aw16; qb.C = gcat + 512;
  qb.K = 2048; qb.ldA = 2048; qb.ldB = 2048; qb.ldC = 1024; qb.z0 = 0;
  qb.ntx = 256; qb.nty = 2; qb.nz = 1;
  gemm_hfha<<<1024, 256, 0, stream>>>(qa, qb);
  // out = hf*sig(gcat*[g1|g2]^T + gbias) + ha*(1-sig(...))  (fused gate+mix)
  q = GP{};
  q.A = gcat; q.B = gw16; q.C = out; q.bias = gbias; q.aux = gcat;
  q.K = 1024; q.ldA = 1024; q.ldB = 1024; q.ldC = 512; q.z0 = 0;
  q.ntx = 256; q.nty = 2; q.nz = 1; q.sBiasH = 0;
  gemm_gate<<<512, 256, 0, stream>>>(q);
}